// Round 6
// baseline (141.612 us; speedup 1.0000x reference)
//
#include <hip/hip_runtime.h>
#include <hip/hip_bf16.h>
#include <cstdint>
#include <cstddef>

// B=4, C=128, L=4096, H=4 (hd=32), GROUPS=32, EPS=1e-5
// gn_stats (split stats: 2 blocks/group, partial sums; + weight cvt)
// -> MFMA qkv (gn finalize in-block; gn inline; Qt/Kt bf16 [l][32], Vb fp16 [32][l])
// -> MFMA flash attention v7 (this round):
//      Q-SPLIT: 64-q blocks, 8 waves = 2 q-tiles(32q) x 4 s-stripes(32s of 128-s iter
//      tile). Grid (64,16)=1024 blocks = 4 blocks/CU = 32 waves/CU (100% slots).
//      2-buffer LDS (36KB incl. epilogue overlay) to fit 4 blocks/CU.
//      K-swizzle FIX: rotation by (row>>1)&3 (old (row)&3 aliased lanes r,r+4 ->
//      2-way conflict = the measured 8 extra cyc/b128). V swizzle unchanged.
//      Same verified per-wave math (32x32 QK/PV MFMA, permlane repack, fdot2 l).
// -> MFMA proj (+bias +raw-x residual), reads bf16 ot.
//
// ws layout (bytes):
//   wq_b  bf16 49,152   @ 0
//   wp_b  bf16 16,384   @ 98,304
//   bp_f  f32  128      @ 131,072
//   gpart f32x2 2,048   @ 131,584   [b][g][half] (s, ss)
//   Qt    bf16 2,097,152 @ 8,388,608   [b*H+h][l][32]
//   Kt    bf16 2,097,152 @ 12,582,912  [b*H+h][l][32]
//   Vb    fp16 2,097,152 @ 16,777,216  [b*H+h][32][l]
//   ot    bf16 2,097,152 @ 20,971,520  [b][l][128]

#define B_ 4
#define C_ 128
#define L_ 4096
#define H_ 4
#define HD_ 32
#define NG_ 32
#define CPG_ 4
#define EPS_ 1e-5f
#define QKSCALE_ 0.5050097650430367f  // 32^(-1/4) * sqrt(log2 e)

typedef __attribute__((ext_vector_type(8))) short bf16x8;
typedef __attribute__((ext_vector_type(8))) unsigned short u16x8;
typedef __attribute__((ext_vector_type(4))) float f32x4;
typedef __attribute__((ext_vector_type(16))) float f32x16;
typedef __attribute__((ext_vector_type(2))) _Float16 f16x2;
typedef __attribute__((ext_vector_type(4))) _Float16 f16x4;
typedef __attribute__((ext_vector_type(8))) _Float16 f16x8;
typedef __attribute__((ext_vector_type(2))) unsigned int u32x2;
typedef __attribute__((ext_vector_type(4))) unsigned int u32x4;

#if __has_builtin(__builtin_amdgcn_exp2f)
#define EXP2F(x) __builtin_amdgcn_exp2f(x)
#else
#define EXP2F(x) exp2f(x)
#endif

__device__ __forceinline__ float bu2f(unsigned short u) {
  return __builtin_bit_cast(float, (unsigned int)(((unsigned int)u) << 16));
}
__device__ __forceinline__ unsigned short f2bu(float f) {
  unsigned int u = __builtin_bit_cast(unsigned int, f);
  unsigned int r = (u + 0x7fffu + ((u >> 16) & 1u)) >> 16;  // RNE
  return (unsigned short)r;
}
__device__ __forceinline__ float4 u42f4(ushort4 u) {
  return make_float4(bu2f(u.x), bu2f(u.y), bu2f(u.z), bu2f(u.w));
}
__device__ __forceinline__ unsigned int pkbf(float a, float b) {
  return (unsigned int)f2bu(a) | ((unsigned int)f2bu(b) << 16);
}
__device__ __forceinline__ f16x2 pkhf2(float a, float b) {
#if __has_builtin(__builtin_amdgcn_cvt_pkrtz)
  return __builtin_bit_cast(f16x2, __builtin_amdgcn_cvt_pkrtz(a, b));
#else
  f16x2 r;
  r[0] = (_Float16)a;
  r[1] = (_Float16)b;
  return r;
#endif
}
__device__ __forceinline__ unsigned int pkhf(float a, float b) {
  return __builtin_bit_cast(unsigned int, pkhf2(a, b));
}

// async global->LDS DMA, 16B per lane. LDS dest must be wave-uniform base + lane*16.
__device__ __forceinline__ void gload16(const void* g, void* l) {
  __builtin_amdgcn_global_load_lds(
      (const __attribute__((address_space(1))) unsigned int*)g,
      (__attribute__((address_space(3))) unsigned int*)l, 16, 0, 0);
}

// fp32-vs-bf16 detection via wave-0 ballot — proven R9.
__device__ __forceinline__ bool detect_fast(const ushort* x) {
  __shared__ int flag_s;
  int t = threadIdx.x;
  if (t < 64) {
    int e = (x[t] >> 7) & 0xFF;
    unsigned long long m = __ballot((e < 64) || (e > 192));
    if (t == 0) flag_s = (__popcll(m) > 4) ? 1 : 0;
  }
  __syncthreads();
  return flag_s != 0;
}

__device__ __forceinline__ float4 ldx4(const void* x, size_t idx, bool f32) {
  if (f32) return *((const float4*)x + (idx >> 2));
  ushort4 u = *((const ushort4*)x + (idx >> 2));
  return u42f4(u);
}

// ---------------------------------------------------------------- GN stats + weight cvt
// Stats split: 2 blocks per (b,g), each reduces a 2048-L half of all 4 channels and
// stores a raw partial (s, ss) — no atomics, finalized inside qkv.
__global__ __launch_bounds__(256) void gn_stats(const void* __restrict__ x,
                                                const void* __restrict__ wq,
                                                const void* __restrict__ wp,
                                                const void* __restrict__ bp,
                                                ushort* __restrict__ wq_b,
                                                ushort* __restrict__ wp_b,
                                                float* __restrict__ bp_f,
                                                float2* __restrict__ gpart) {
  bool f32 = detect_fast((const ushort*)x);
  int blk = blockIdx.x;
  int t = threadIdx.x;

  if (blk >= 256) {
    int i0 = ((blk - 256) * 256 + t) * 8;
#pragma unroll
    for (int k = 0; k < 8; ++k) {
      int i = i0 + k;
      if (i >= 65664) break;
      if (i < 49152) {
        wq_b[i] = f32 ? f2bu(((const float*)wq)[i]) : ((const ushort*)wq)[i];
      } else if (i < 65536) {
        int off = i - 49152;
        wp_b[off] = f32 ? f2bu(((const float*)wp)[off]) : ((const ushort*)wp)[off];
      } else {
        int off = i - 65536;
        bp_f[off] = f32 ? ((const float*)bp)[off] : bu2f(((const ushort*)bp)[off]);
      }
    }
    return;
  }

  int b = blk >> 6, rem = blk & 63;
  int g = rem >> 1, half = rem & 1;
  size_t base = ((size_t)b * C_ + (size_t)g * CPG_) * L_ + (size_t)half * 2048;

  float s = 0.f, ss = 0.f;
#pragma unroll
  for (int cc = 0; cc < 4; ++cc) {
#pragma unroll
    for (int i = 0; i < 2; ++i) {
      size_t e = base + (size_t)cc * L_ + i * 1024 + t * 4;
      float4 f = ldx4(x, e, f32);
      s += f.x + f.y + f.z + f.w;
      ss += f.x * f.x + f.y * f.y + f.z * f.z + f.w * f.w;
    }
  }
#pragma unroll
  for (int m = 32; m >= 1; m >>= 1) {
    s += __shfl_xor(s, m, 64);
    ss += __shfl_xor(ss, m, 64);
  }
  __shared__ float red[4][2];
  int wv = t >> 6;
  if ((t & 63) == 0) { red[wv][0] = s; red[wv][1] = ss; }
  __syncthreads();
  if (t == 0) {
    float ts = red[0][0] + red[1][0] + red[2][0] + red[3][0];
    float tss = red[0][1] + red[1][1] + red[2][1] + red[3][1];
    gpart[(b * 32 + g) * 2 + half] = make_float2(ts, tss);
  }
}

// ---------------------------------------------------------------- QKV GEMM (MFMA, gn inline)
// GN finalize in-block from gpart partials (cheap, redundant per block).
__global__ __launch_bounds__(256) void qkv_kernel(const ushort* __restrict__ wq_b,
                                                  const void* __restrict__ x,
                                                  const float2* __restrict__ gpart,
                                                  const void* __restrict__ gm,
                                                  const void* __restrict__ bt,
                                                  ushort* __restrict__ Qt,
                                                  ushort* __restrict__ Kt,
                                                  ushort* __restrict__ Vb) {
  bool f32 = detect_fast((const ushort*)x);
  __shared__ alignas(16) ushort Hs[64][136];
  __shared__ alignas(16) float Ls[64][69];
  __shared__ float2 abs_s[128];

  int lx = blockIdx.x, oz = blockIdx.y, b = blockIdx.z;
  int t = threadIdx.x;
  int w = t >> 6, lane = t & 63, l16 = lane & 15, q = lane >> 4, q8 = q * 8;

  if (t < 64) {
#pragma unroll
    for (int k = 0; k < 2; ++k) {
      int c = 2 * t + k;
      int g = c >> 2;
      float2 p0 = gpart[(b * 32 + g) * 2];
      float2 p1 = gpart[(b * 32 + g) * 2 + 1];
      float mu = (p0.x + p1.x) * (1.0f / 16384.0f);
      float var = (p0.y + p1.y) * (1.0f / 16384.0f) - mu * mu;
      float rs = rsqrtf(var + EPS_);
      float ga = f32 ? ((const float*)gm)[c] : bu2f(((const ushort*)gm)[c]);
      float be = f32 ? ((const float*)bt)[c] : bu2f(((const ushort*)bt)[c]);
      abs_s[c] = make_float2(ga * rs, be - mu * ga * rs);
    }
  }
  __syncthreads();

  {
    int u = t & 63, lh = (t >> 6) * 16;
    int c0 = 2 * u;
    float2 ab0 = abs_s[c0];
    float2 ab1 = abs_s[c0 + 1];
    size_t xo = ((size_t)b * C_ + c0) * L_ + (size_t)lx * 64 + lh;
#pragma unroll
    for (int j = 0; j < 4; ++j) {
      float4 f0 = ldx4(x, xo + j * 4, f32);
      float4 f1 = ldx4(x, xo + L_ + j * 4, f32);
      float n0[4] = {f0.x * ab0.x + ab0.y, f0.y * ab0.x + ab0.y,
                     f0.z * ab0.x + ab0.y, f0.w * ab0.x + ab0.y};
      float n1[4] = {f1.x * ab1.x + ab1.y, f1.y * ab1.x + ab1.y,
                     f1.z * ab1.x + ab1.y, f1.w * ab1.x + ab1.y};
#pragma unroll
      for (int k = 0; k < 4; ++k)
        *(unsigned int*)&Hs[lh + j * 4 + k][c0] = pkbf(n0[k], n1[k]);
    }
  }
  __syncthreads();

  for (int j = 0; j < 2; ++j) {
    int oy = oz * 2 + j;
    const ushort* wg = wq_b + (size_t)(oy * 64 + w * 16 + l16) * C_;

    f32x4 acc[4] = {{0.f, 0.f, 0.f, 0.f}, {0.f, 0.f, 0.f, 0.f},
                    {0.f, 0.f, 0.f, 0.f}, {0.f, 0.f, 0.f, 0.f}};
#pragma unroll
    for (int kc = 0; kc < 4; ++kc) {
      bf16x8 aw = *(const bf16x8*)(wg + kc * 32 + q8);
#pragma unroll
      for (int nb = 0; nb < 4; ++nb) {
        bf16x8 bh = *(const bf16x8*)&Hs[nb * 16 + l16][kc * 32 + q8];
        acc[nb] = __builtin_amdgcn_mfma_f32_16x16x32_bf16(aw, bh, acc[nb], 0, 0, 0);
      }
    }
    __syncthreads();
#pragma unroll
    for (int nb = 0; nb < 4; ++nb)
#pragma unroll
      for (int r = 0; r < 4; ++r)
        Ls[nb * 16 + l16][w * 16 + 4 * q + r] = acc[nb][r];
    __syncthreads();

#pragma unroll
    for (int hhalf = 0; hhalf < 2; ++hhalf) {
      int hh = oy * 2 + hhalf;
      int type = hh % 3, head = hh / 3;
      size_t bh = (size_t)b * H_ + head;
      if (type == 2) {
        int c_loc = t >> 3, l8 = (t & 7) * 8;
        float v[8];
#pragma unroll
        for (int jj = 0; jj < 8; ++jj) v[jj] = Ls[l8 + jj][hhalf * 32 + c_loc];
        uint4 u;
        u.x = pkhf(v[0], v[1]);
        u.y = pkhf(v[2], v[3]);
        u.z = pkhf(v[4], v[5]);
        u.w = pkhf(v[6], v[7]);
        *(uint4*)(Vb + (bh * 32 + c_loc) * L_ + (size_t)lx * 64 + l8) = u;
      } else {
        ushort* dst = type ? Kt : Qt;
        int l = t >> 2, seg = (t & 3) * 8;
        const float* src = &Ls[l][hhalf * 32 + seg];
        uint4 u;
        u.x = pkbf(src[0] * QKSCALE_, src[1] * QKSCALE_);
        u.y = pkbf(src[2] * QKSCALE_, src[3] * QKSCALE_);
        u.z = pkbf(src[4] * QKSCALE_, src[5] * QKSCALE_);
        u.w = pkbf(src[6] * QKSCALE_, src[7] * QKSCALE_);
        *(uint4*)(dst + ((bh * L_) + lx * 64 + l) * 32 + seg) = u;
      }
    }
  }
}

// ---------------------------------------------------------------- MFMA flash attention v7
// 64-q blocks, 8 waves = 2 q-tiles (qt=w&1) x 4 s-stripes (sh=w>>1), 128 s per iter.
// K LDS [128 s][4 chunks], phys chunk = (c_sem + (row>>1)) & 3  (period-8 rotation ->
// truly conflict-free b128 reads). V LDS [32 c][16 chunks], chunk = (c&8)|((c&7)^(row&7)).
// Both staged via global_load_lds from pre-swizzled global sources. 2-buffer + barrier.
__global__ __launch_bounds__(512, 8) void attn_kernel(const ushort* __restrict__ Qt,
                                                      const ushort* __restrict__ Kt,
                                                      const ushort* __restrict__ Vb,
                                                      ushort* __restrict__ ot) {
  // K bufs: [0,8192),[8192,16384) ; V bufs: [16384,24576),[24576,32768)
  // epilogue overlay: Osh [8][32][33] f32 = 33792B @0 ; Lp [8][64] f32 @33792 (2048B)
  __shared__ alignas(16) char smem[35840];

  int t = threadIdx.x;
  int w = t >> 6, lane = t & 63, l31 = lane & 31, hi = lane >> 5;
  int qt = w & 1, sh = w >> 1;
  int tq0 = blockIdx.x * 64;
  int bh = blockIdx.y;
  int b = bh >> 2, head = bh & 3;
  const ushort* Qg = Qt + ((size_t)bh * L_ + tq0) * 32;
  const ushort* Kg = Kt + (size_t)bh * L_ * 32;
  const ushort* Vg = Vb + (size_t)bh * 32 * L_;

  // staging sources (pre-swizzled so linear DMA dest yields swizzled LDS)
  int rd = t >> 2, pd = t & 3;
  int kcsem = (pd - (rd >> 1)) & 3;
  const ushort* ksrc = Kg + (size_t)rd * 32 + kcsem * 8;
  int vr = t >> 4, vp = t & 15;
  int vcsem = (vp & 8) | ((vp & 7) ^ (vr & 7));
  const ushort* vsrc = Vg + (size_t)vr * L_ + vcsem * 8;

  char* kb0 = smem;
  char* kb1 = smem + 8192;
  char* vb0 = smem + 16384;
  char* vb1 = smem + 24576;

  // Q fragments (B operand): lane holds Q[q=qt*32+l31][k = 8*hi + j] (+16 for 2nd K-half)
  const ushort* qbase = Qg + (size_t)(qt * 32 + l31) * 32;
  bf16x8 qB0 = *(const bf16x8*)(qbase + 8 * hi);
  bf16x8 qB1 = *(const bf16x8*)(qbase + 16 + 8 * hi);

  const f16x2 one2 = {(_Float16)1.0f, (_Float16)1.0f};
  const f32x16 zz = {0.f};

  // prologue: DMA tile 0 into buf A
  gload16(ksrc, kb0 + (size_t)t * 16);
  gload16(vsrc, vb0 + (size_t)t * 16);
  ksrc += 4096;
  vsrc += 128;
  __syncthreads();

  f32x16 aO = {0.f};
  float lsum = 0.f;
  int s0 = 32 * sh;
  int rot = (l31 >> 1) & 3;

  int flip = 0;
  for (int it = 0; it < 32; ++it) {
    if (it < 31) {
      gload16(ksrc, (flip ? kb0 : kb1) + (size_t)t * 16);
      gload16(vsrc, (flip ? vb0 : vb1) + (size_t)t * 16);
      ksrc += 4096;
      vsrc += 128;
    }
    const ushort* kc = (const ushort*)(flip ? kb1 : kb0);
    const ushort* vc = (const ushort*)(flip ? vb1 : vb0);

    const ushort* krow = kc + (size_t)(s0 + l31) * 32;
    bf16x8 aK0 = *(const bf16x8*)(krow + ((hi + rot) & 3) * 8);
    bf16x8 aK1 = *(const bf16x8*)(krow + ((2 + hi + rot) & 3) * 8);
    f32x16 sf;
    __builtin_amdgcn_s_setprio(1);
    sf = __builtin_amdgcn_mfma_f32_32x32x16_bf16(aK0, qB0, zz, 0, 0, 0);
    sf = __builtin_amdgcn_mfma_f32_32x32x16_bf16(aK1, qB1, sf, 0, 0, 0);
    __builtin_amdgcn_s_setprio(0);

#pragma unroll
    for (int sb = 0; sb < 2; ++sb) {
      int sblk = 2 * sh + sb;
      // V fragment (A operand): V[c=l31][s = sblk*16 + 8*hi + j]
      int kci = 2 * sblk + hi;
      int vpos = (kci & 8) | ((kci & 7) ^ (l31 & 7));
      f16x8 vf = *(const f16x8*)(vc + (size_t)l31 * 128 + vpos * 8);

      float p0 = EXP2F(sf[8 * sb + 0]);
      float p1 = EXP2F(sf[8 * sb + 1]);
      float p2 = EXP2F(sf[8 * sb + 2]);
      float p3 = EXP2F(sf[8 * sb + 3]);
      float p4 = EXP2F(sf[8 * sb + 4]);
      float p5 = EXP2F(sf[8 * sb + 5]);
      float p6 = EXP2F(sf[8 * sb + 6]);
      float p7 = EXP2F(sf[8 * sb + 7]);
      f16x2 cA0 = pkhf2(p0, p1), cA1 = pkhf2(p2, p3);
      f16x2 cB0 = pkhf2(p4, p5), cB1 = pkhf2(p6, p7);
      lsum = __builtin_amdgcn_fdot2(cA0, one2, lsum, false);
      lsum = __builtin_amdgcn_fdot2(cA1, one2, lsum, false);
      lsum = __builtin_amdgcn_fdot2(cB0, one2, lsum, false);
      lsum = __builtin_amdgcn_fdot2(cB1, one2, lsum, false);

      // B-fragment repack: (w0,w2) = swap(cA0, cB0); (w1,w3) = swap(cA1, cB1)
      u32x2 r0 = __builtin_amdgcn_permlane32_swap(
          __builtin_bit_cast(unsigned int, cA0),
          __builtin_bit_cast(unsigned int, cB0), false, false);
      u32x2 r1 = __builtin_amdgcn_permlane32_swap(
          __builtin_bit_cast(unsigned int, cA1),
          __builtin_bit_cast(unsigned int, cB1), false, false);
      u32x4 pw = {r0.x, r1.x, r0.y, r1.y};
      f16x8 pf = __builtin_bit_cast(f16x8, pw);

      __builtin_amdgcn_s_setprio(1);
      aO = __builtin_amdgcn_mfma_f32_32x32x16_f16(vf, pf, aO, 0, 0, 0);
      __builtin_amdgcn_s_setprio(0);
    }
    __syncthreads();
    flip ^= 1;
  }

  // ---- epilogue: write partials (padded rows: bank = (l31 + word) % 32, conflict-free)
  float* Osh = (float*)smem;                // [slot=sh*2+qt][q=32][c=33pad]
  float* Lp = (float*)(smem + 33792);       // [sh*2+hi][64]
  {
    float* ob = Osh + (size_t)(sh * 2 + qt) * (32 * 33) + (size_t)l31 * 33;
#pragma unroll
    for (int reg = 0; reg < 16; ++reg) {
      int R = (reg & 3) + 8 * (reg >> 2) + 4 * hi;
      ob[R] = aO[reg];
    }
    Lp[(sh * 2 + hi) * 64 + qt * 32 + l31] = lsum;
  }
  __syncthreads();

  // combine 4 s-stripes (+2 hi per stripe in Lp), normalize, pack bf16, store
  {
    int qloc = t >> 3, seg = (t & 7) * 4;
    int qt2 = qloc >> 5, q31 = qloc & 31;
    float lt = 0.f;
#pragma unroll
    for (int k = 0; k < 8; ++k) lt += Lp[k * 64 + qloc];
    float inv = 1.0f / lt;
    float o[4] = {0.f, 0.f, 0.f, 0.f};
#pragma unroll
    for (int s = 0; s < 4; ++s) {
      const float* op = Osh + (size_t)(s * 2 + qt2) * (32 * 33) + (size_t)q31 * 33 + seg;
#pragma unroll
      for (int jj = 0; jj < 4; ++jj) o[jj] += op[jj];
    }
    uint2 u;
    u.x = pkbf(o[0] * inv, o[1] * inv);
    u.y = pkbf(o[2] * inv, o[3] * inv);
    *(uint2*)(ot + ((size_t)b * L_ + tq0 + qloc) * C_ + head * 32 + seg) = u;
  }
}

// ---------------------------------------------------------------- Proj + bias + residual
__global__ __launch_bounds__(256) void proj_kernel(const ushort* __restrict__ wp_b,
                                                   const float* __restrict__ bias,
                                                   const void* __restrict__ x,
                                                   const ushort* __restrict__ ot,
                                                   void* __restrict__ out) {
  bool f32 = detect_fast((const ushort*)x);
  __shared__ alignas(16) float Ls[64][37];

  int lx = blockIdx.x, oy = blockIdx.y, b = blockIdx.z;
  int t = threadIdx.x;
  int w = t >> 6, lane = t & 63, l16 = lane & 15, q = lane >> 4, q8 = q * 8;

  const ushort* wg = wp_b + (size_t)(oy * 64 + w * 16 + l16) * C_;
  const ushort* og = ot + ((size_t)b * L_ + (size_t)lx * 32) * C_;

  f32x4 acc[2] = {{0.f, 0.f, 0.f, 0.f}, {0.f, 0.f, 0.f, 0.f}};
#pragma unroll
  for (int kc = 0; kc < 4; ++kc) {
    bf16x8 aw = *(const bf16x8*)(wg + kc * 32 + q8);
#pragma unroll
    for (int nb = 0; nb < 2; ++nb) {
      bf16x8 bo = *(const bf16x8*)(og + (size_t)(nb * 16 + l16) * C_ + kc * 32 + q8);
      acc[nb] = __builtin_amdgcn_mfma_f32_16x16x32_bf16(aw, bo, acc[nb], 0, 0, 0);
    }
  }
#pragma unroll
  for (int nb = 0; nb < 2; ++nb)
#pragma unroll
    for (int r = 0; r < 4; ++r)
      Ls[w * 16 + 4 * q + r][nb * 16 + l16] = acc[nb][r];
  __syncthreads();

  {
    int o_loc = t >> 2, ls0 = (t & 3) * 8;
    float bv = bias[oy * 64 + o_loc];
    size_t off = ((size_t)b * C_ + oy * 64 + o_loc) * L_ + (size_t)lx * 32 + ls0;
#pragma unroll
    for (int jj = 0; jj < 2; ++jj) {
      float4 xf = ldx4(x, off + jj * 4, f32);
      const float* sp = &Ls[o_loc][ls0 + jj * 4];
      float4 r = make_float4(sp[0] + bv + xf.x, sp[1] + bv + xf.y,
                             sp[2] + bv + xf.z, sp[3] + bv + xf.w);
      if (f32) {
        *(float4*)((float*)out + off + jj * 4) = r;
      } else {
        *(ushort4*)((ushort*)out + off + jj * 4) =
            make_ushort4(f2bu(r.x), f2bu(r.y), f2bu(r.z), f2bu(r.w));
      }
    }
  }
}

// ---------------------------------------------------------------- launch
extern "C" void kernel_launch(void* const* d_in, const int* in_sizes, int n_in,
                              void* d_out, int out_size, void* d_ws, size_t ws_size,
                              hipStream_t stream) {
  const void* x      = d_in[0];
  const void* w_qkv  = d_in[1];
  const void* w_proj = d_in[2];
  const void* b_proj = d_in[3];
  const void* gamma  = d_in[4];
  const void* beta   = d_in[5];

  char* wsb = (char*)d_ws;
  ushort* wq_b  = (ushort*)(wsb + 0);
  ushort* wp_b  = (ushort*)(wsb + 98304);
  float*  bp_f  = (float*)(wsb + 131072);
  float2* gpart = (float2*)(wsb + 131584);
  ushort* Qt    = (ushort*)(wsb + 8388608);
  ushort* Kt    = (ushort*)(wsb + 12582912);
  ushort* Vb    = (ushort*)(wsb + 16777216);  // fp16
  ushort* ot    = (ushort*)(wsb + 20971520);

  gn_stats<<<dim3(289), dim3(256), 0, stream>>>(x, w_qkv, w_proj, b_proj,
                                                wq_b, wp_b, bp_f, gpart);
  qkv_kernel<<<dim3(L_ / 64, 3, B_), dim3(256), 0, stream>>>(wq_b, x, gpart, gamma, beta,
                                                             Qt, Kt, Vb);
  attn_kernel<<<dim3(L_ / 64, B_ * H_), dim3(512), 0, stream>>>(Qt, Kt, Vb, ot);
  proj_kernel<<<dim3(L_ / 32, C_ / 64, B_), dim3(256), 0, stream>>>(wp_b, bp_f, x, ot, d_out);
}